// Round 9
// baseline (67.407 us; speedup 1.0000x reference)
//
#include <hip/hip_runtime.h>

// MPDNN SchNet-style MPNN, 5-dispatch pipeline.
// R2: cooperative grid.sync ~120us/barrier on gfx950 -> multi-dispatch chain.
// R8 (53.2us) anchor: XCD-affinity swizzle + direct-L2 gathers. R9: replace
// cross-thread LDS reductions with intra-wave shuffle reductions — conv loses
// 3 of 6 barriers + all 3 staging stages (m_s, red x2); edgepool loses s_s.
// Lane layout: g = w*16+(l&15), f-slice f = 4c+(l>>4) (bank-conflict-free),
// reduce via shfl_xor(16)+shfl_xor(32). h_in residual prefetched at start.
//  - Wf(d) -> 4096-row bf16 lookup table (1 MB, per-XCD L2 copy)
//  - compact neighbor lists (d<6, ~23% dense), entry = j | (table_row<<7)
//  - conv3 fuses NodePool + pre_i/pre_j; c_aniso.sum(j) pushed through @We2

#define LN2F 0.69314718055994531f

__device__ __forceinline__ float sspf(float x) {          // softplus(x) - ln2, stable
  float e = __expf(-fabsf(x));
  return fmaxf(x, 0.0f) + __logf(1.0f + e) - LN2F;
}
__device__ __forceinline__ unsigned int f2bf(float x) {   // fp32 -> bf16 bits (RNE)
  unsigned int u = __float_as_uint(x);
  return (u + 0x7fffu + ((u >> 16) & 1u)) >> 16;
}
__device__ __forceinline__ float bflo(unsigned int u) { return __uint_as_float(u << 16); }
__device__ __forceinline__ float bfhi(unsigned int u) { return __uint_as_float(u & 0xffff0000u); }

// ---------------------------------------------------------------------------
// prep: unchanged from R8 (proven).
// ---------------------------------------------------------------------------
__global__ __launch_bounds__(256) void prep_kernel(
    const float* __restrict__ coords, const int* __restrict__ species,
    const float* __restrict__ emb,
    const float* __restrict__ Wc1, const float* __restrict__ bc1,
    const float* __restrict__ Wc2, const float* __restrict__ bc2,
    unsigned int* __restrict__ tb16, float* __restrict__ h_a,
    unsigned int* __restrict__ hbf_a,
    unsigned int* __restrict__ ent, int* __restrict__ cnt) {
  int t = threadIdx.x;
  if (blockIdx.x < 1024) {
    __shared__ int wc[4];
    int blk = (int)blockIdx.x;
    int Lb = ((blk & 7) << 7) | (blk >> 3);         // XCD-affinity swizzle (1024)
    int node = Lb * 2 + (t >> 7);
    int j = t & 127;
    int b = node >> 7, i = node & 127;
    const float* cb = coords + (b << 7) * 3;
    float dx = cb[i*3+0] - cb[j*3+0];
    float dy = cb[i*3+1] - cb[j*3+1];
    float dz = cb[i*3+2] - cb[j*3+2];
    float d  = sqrtf(dx*dx + dy*dy + dz*dz);
    bool valid = (d < 6.0f) && (j != i);
    int k = 4096;                                   // 4096 = zero table row (pad)
    if (valid) { k = (int)(d * (4096.0f/6.0f)); if (k > 4095) k = 4095; }
    unsigned long long bal = __ballot(valid);
    int lane = t & 63, w = t >> 6;
    if (lane == 0) wc[w] = (int)__popcll(bal);
    __syncthreads();
    int ii = t >> 7;
    int nn = wc[2*ii] + wc[2*ii+1];
    int base = ((w & 1) ? wc[w-1] : 0) + (int)__popcll(bal & ((1ull << lane) - 1ull));
    if (valid) ent[node*128 + base] = (unsigned int)(j | (k << 7));
    int nnp = (nn + 15) & ~15;                      // pad x16 (8-deep gather)
    if (nnp > 128) nnp = 128;
    if (j >= nn && j < nnp) ent[node*128 + j] = (4096u << 7);
    if (j == 0) cnt[node] = nn | (nnp << 16);
    float hv = emb[species[node]*128 + j];
    h_a[node*128 + j] = hv;
    unsigned int lo = f2bf(hv);
    unsigned int hi = (unsigned int)__shfl_xor((int)lo, 1);
    if ((j & 1) == 0) hbf_a[node*64 + (j >> 1)] = lo | (hi << 16);
  } else {
    __shared__ float rbf[8][32];
    __shared__ float hid[8][128];
    int tb = (int)blockIdx.x - 1024;                // 0..511
    int t0 = tb * 8;
    { int tt = t >> 5, kk = t & 31;                 // 256 threads = 8x32 exactly
      float d = (float)(t0 + tt) * (6.0f/4096.0f) + 0.5f * (6.0f/4096.0f);
      float mu = 0.5f + (float)kk * (5.5f/31.0f);
      float z = d - mu;
      rbf[tt][kk] = __expf(-8.0f * z * z); }        // 1/(2*0.25^2)=8
    __syncthreads();
    int f = t & 127, sub = t >> 7;                  // sub in 0..1 -> rows sub*4..+3
    float s0 = bc1[f], s1 = s0, s2 = s0, s3 = s0;
    int r0 = sub * 4;
    for (int kk = 0; kk < 32; kk++) {
      float wv = Wc1[kk*128 + f];
      s0 += rbf[r0+0][kk]*wv; s1 += rbf[r0+1][kk]*wv;
      s2 += rbf[r0+2][kk]*wv; s3 += rbf[r0+3][kk]*wv;
    }
    hid[r0+0][f] = sspf(s0); hid[r0+1][f] = sspf(s1);
    hid[r0+2][f] = sspf(s2); hid[r0+3][f] = sspf(s3);
    __syncthreads();
    float o0 = bc2[f], o1 = o0, o2 = o0, o3 = o0;
    for (int g = 0; g < 128; g++) {
      float wv = Wc2[g*128 + f];
      o0 += hid[r0+0][g]*wv; o1 += hid[r0+1][g]*wv;
      o2 += hid[r0+2][g]*wv; o3 += hid[r0+3][g]*wv;
    }
    unsigned int l0 = f2bf(o0), l1 = f2bf(o1), l2 = f2bf(o2), l3 = f2bf(o3);
    unsigned int p0 = (unsigned int)__shfl_xor((int)l0, 1);
    unsigned int p1 = (unsigned int)__shfl_xor((int)l1, 1);
    unsigned int p2 = (unsigned int)__shfl_xor((int)l2, 1);
    unsigned int p3 = (unsigned int)__shfl_xor((int)l3, 1);
    if ((f & 1) == 0) {
      int fw = f >> 1;
      tb16[(t0+r0+0)*64 + fw] = l0 | (p0 << 16);
      tb16[(t0+r0+1)*64 + fw] = l1 | (p1 << 16);
      tb16[(t0+r0+2)*64 + fw] = l2 | (p2 << 16);
      tb16[(t0+r0+3)*64 + fw] = l3 | (p3 << 16);
    }
    if (tb == 0 && t < 64) tb16[4096*64 + t] = 0u;  // zero pad row
  }
}

// ---------------------------------------------------------------------------
// conv: one block = 4 nodes (swizzled). Direct L2 gather (8 in flight each),
// update net via intra-wave shuffle reduction (3 barriers, no LDS staging).
// LAST: skip h stores; fuse NodePool (c_iso) + pre_i/pre_j.
// ---------------------------------------------------------------------------
template<bool LAST>
__global__ __launch_bounds__(512) void conv_t(
    const float* __restrict__ h_in, const unsigned int* __restrict__ hbf_in,
    float* __restrict__ h_out, unsigned int* __restrict__ hbf_out,
    const unsigned int* __restrict__ tb16, const unsigned int* __restrict__ ent,
    const int* __restrict__ cnt,
    const float* __restrict__ Wu1, const float* __restrict__ bu1,
    const float* __restrict__ Wu2, const float* __restrict__ bu2,
    const float* __restrict__ Wp1, const float* __restrict__ bp1,
    const float* __restrict__ Wp2, const float* __restrict__ bp2,
    const float* __restrict__ Wei, const float* __restrict__ Wej,
    float* __restrict__ pre_i, unsigned int* __restrict__ prejbf,
    float* __restrict__ out) {
  __shared__ unsigned int ent_s[4][128];
  __shared__ float mred[8][128];
  __shared__ float u1_s[4][128];
  __shared__ int nn_s[4];
  int t = threadIdx.x;
  int blk = (int)blockIdx.x;
  int Lb = ((blk & 7) << 6) | (blk >> 3);   // XCD-affinity swizzle (512)
  int node0 = Lb * 4;
  int b = Lb >> 5;
  const unsigned int* hb = hbf_in + (b << 13);   // batch's bf16 h panel (L2)

  { int ii = t >> 7, f = t & 127;
    ent_s[ii][f] = ent[(node0 + ii)*128 + f]; }
  if (t < 4) nn_s[t] = cnt[node0 + t];

  int w = t >> 6, lane = t & 63;
  int gl = lane & 15, seg = lane >> 4;
  int g = w * 16 + gl;
  // prefetch residual (needed only at the end; hides L2 latency)
  float hr0 = h_in[(node0+0)*128 + g];
  float hr1 = h_in[(node0+1)*128 + g];
  float hr2 = h_in[(node0+2)*128 + g];
  float hr3 = h_in[(node0+3)*128 + g];
  __syncthreads();

  // --- message: wave pair by parity, 8 table + 8 h gathers in flight ---
  int ii = w >> 1, par = w & 1;
  int nnp = nn_s[ii] >> 16;                 // padded count (multiple of 16)
  float a0 = 0.f, a1 = 0.f, b0 = 0.f, b1 = 0.f;
  float c0 = 0.f, c1 = 0.f, d0 = 0.f, d1 = 0.f;
  for (int e = par; e < nnp; e += 16) {
    unsigned int u0 = ent_s[ii][e],      u1 = ent_s[ii][e + 2];
    unsigned int u2 = ent_s[ii][e + 4],  u3 = ent_s[ii][e + 6];
    unsigned int u4 = ent_s[ii][e + 8],  u5 = ent_s[ii][e + 10];
    unsigned int u6 = ent_s[ii][e + 12], u7 = ent_s[ii][e + 14];
    unsigned int t0 = tb16[(u0 >> 7)*64 + lane];
    unsigned int t1 = tb16[(u1 >> 7)*64 + lane];
    unsigned int t2 = tb16[(u2 >> 7)*64 + lane];
    unsigned int t3 = tb16[(u3 >> 7)*64 + lane];
    unsigned int t4 = tb16[(u4 >> 7)*64 + lane];
    unsigned int t5 = tb16[(u5 >> 7)*64 + lane];
    unsigned int t6 = tb16[(u6 >> 7)*64 + lane];
    unsigned int t7 = tb16[(u7 >> 7)*64 + lane];
    unsigned int h0 = hb[(u0 & 127)*64 + lane];
    unsigned int h1 = hb[(u1 & 127)*64 + lane];
    unsigned int h2 = hb[(u2 & 127)*64 + lane];
    unsigned int h3 = hb[(u3 & 127)*64 + lane];
    unsigned int h4 = hb[(u4 & 127)*64 + lane];
    unsigned int h5 = hb[(u5 & 127)*64 + lane];
    unsigned int h6 = hb[(u6 & 127)*64 + lane];
    unsigned int h7 = hb[(u7 & 127)*64 + lane];
    a0 += bflo(t0) * bflo(h0); a1 += bfhi(t0) * bfhi(h0);
    b0 += bflo(t1) * bflo(h1); b1 += bfhi(t1) * bfhi(h1);
    c0 += bflo(t2) * bflo(h2); c1 += bfhi(t2) * bfhi(h2);
    d0 += bflo(t3) * bflo(h3); d1 += bfhi(t3) * bfhi(h3);
    a0 += bflo(t4) * bflo(h4); a1 += bfhi(t4) * bfhi(h4);
    b0 += bflo(t5) * bflo(h5); b1 += bfhi(t5) * bfhi(h5);
    c0 += bflo(t6) * bflo(h6); c1 += bfhi(t6) * bfhi(h6);
    d0 += bflo(t7) * bflo(h7); d1 += bfhi(t7) * bfhi(h7);
  }
  a0 += b0 + c0 + d0; a1 += b1 + c1 + d1;
  *(float2*)&mred[w][2*lane] = make_float2(a0, a1);
  __syncthreads();

  // --- Wu1: lane (w,l) -> column g, f-slice f = 4c+seg; shuffle-reduce ---
  float p0 = 0.f, p1 = 0.f, p2 = 0.f, p3 = 0.f;
  for (int c2 = 0; c2 < 32; c2++) {
    int f = c2*4 + seg;
    float wv = Wu1[f*128 + g];
    float m0 = mred[0][f] + mred[1][f];
    float m1 = mred[2][f] + mred[3][f];
    float m2 = mred[4][f] + mred[5][f];
    float m3 = mred[6][f] + mred[7][f];
    p0 += m0*wv; p1 += m1*wv; p2 += m2*wv; p3 += m3*wv;
  }
  p0 += __shfl_xor(p0, 16); p0 += __shfl_xor(p0, 32);
  p1 += __shfl_xor(p1, 16); p1 += __shfl_xor(p1, 32);
  p2 += __shfl_xor(p2, 16); p2 += __shfl_xor(p2, 32);
  p3 += __shfl_xor(p3, 16); p3 += __shfl_xor(p3, 32);
  if (seg == 0) {
    float bv = bu1[g];
    u1_s[0][g] = sspf(p0 + bv); u1_s[1][g] = sspf(p1 + bv);
    u1_s[2][g] = sspf(p2 + bv); u1_s[3][g] = sspf(p3 + bv);
  }
  __syncthreads();

  // --- Wu2: same layout; shuffle-reduce; residual add in registers ---
  float q0 = 0.f, q1 = 0.f, q2 = 0.f, q3 = 0.f;
  for (int c2 = 0; c2 < 32; c2++) {
    int f = c2*4 + seg;
    float wv = Wu2[f*128 + g];
    q0 += u1_s[0][f]*wv; q1 += u1_s[1][f]*wv;
    q2 += u1_s[2][f]*wv; q3 += u1_s[3][f]*wv;
  }
  q0 += __shfl_xor(q0, 16); q0 += __shfl_xor(q0, 32);
  q1 += __shfl_xor(q1, 16); q1 += __shfl_xor(q1, 32);
  q2 += __shfl_xor(q2, 16); q2 += __shfl_xor(q2, 32);
  q3 += __shfl_xor(q3, 16); q3 += __shfl_xor(q3, 32);
  float b2v = bu2[g];
  float hf0 = hr0 + q0 + b2v;
  float hf1 = hr1 + q1 + b2v;
  float hf2 = hr2 + q2 + b2v;
  float hf3 = hr3 + q3 + b2v;

  if constexpr (!LAST) {
    if (seg == 0) {
      h_out[(node0+0)*128 + g] = hf0;
      h_out[(node0+1)*128 + g] = hf1;
      h_out[(node0+2)*128 + g] = hf2;
      h_out[(node0+3)*128 + g] = hf3;
    }
    unsigned int l0 = f2bf(hf0), l1 = f2bf(hf1), l2 = f2bf(hf2), l3 = f2bf(hf3);
    unsigned int x0 = (unsigned int)__shfl_xor((int)l0, 1);
    unsigned int x1 = (unsigned int)__shfl_xor((int)l1, 1);
    unsigned int x2 = (unsigned int)__shfl_xor((int)l2, 1);
    unsigned int x3 = (unsigned int)__shfl_xor((int)l3, 1);
    if (seg == 0 && (gl & 1) == 0) {
      int gw = g >> 1;
      hbf_out[(node0+0)*64 + gw] = l0 | (x0 << 16);
      hbf_out[(node0+1)*64 + gw] = l1 | (x1 << 16);
      hbf_out[(node0+2)*64 + gw] = l2 | (x2 << 16);
      hbf_out[(node0+3)*64 + gw] = l3 | (x3 << 16);
    }
  } else {
    __syncthreads();                        // all Wu2 reads of u1_s done
    if (seg == 0) {
      u1_s[0][g] = hf0; u1_s[1][g] = hf1; u1_s[2][g] = hf2; u1_s[3][g] = hf3;
    }
    __syncthreads();
    __shared__ float redp[8][4][64];
    __shared__ float us[4][64];
    float (*hs)[128] = u1_s;
    int gp = t & 63, qp = t >> 6;           // qp 0..7 -> 16-wide f segment
    float r0 = 0.f, r1 = 0.f, r2v = 0.f, r3 = 0.f;
    for (int f = qp*16; f < qp*16 + 16; f++) {
      float wv = Wp1[f*64 + gp];
      r0 += hs[0][f]*wv; r1 += hs[1][f]*wv; r2v += hs[2][f]*wv; r3 += hs[3][f]*wv;
    }
    redp[qp][0][gp]=r0; redp[qp][1][gp]=r1; redp[qp][2][gp]=r2v; redp[qp][3][gp]=r3;
    __syncthreads();
    if (t < 256) {
      int i4 = t >> 6, gg = t & 63;
      float s = bp1[gg];
      for (int q2 = 0; q2 < 8; q2++) s += redp[q2][i4][gg];
      us[i4][gg] = sspf(s);
    }
    __syncthreads();
    if (t < 32) {
      int i4 = t >> 3, o = t & 7;
      float v = bp2[o];
      for (int gg = 0; gg < 64; gg++) v += us[i4][gg] * Wp2[gg*8 + o];
      out[(node0 + i4)*8 + o] = v;
    }
    int o = t & 127, sel = (t >> 7) & 1, duo = t >> 8;
    const float* W = sel ? Wej : Wei;
    float e0 = 0.f, e1 = 0.f;
    for (int f = 0; f < 128; f++) {
      float wv = W[f*128 + o];
      e0 += hs[2*duo][f]*wv; e1 += hs[2*duo+1][f]*wv;
    }
    if (sel == 0) {
      pre_i[(node0 + 2*duo)*128 + o]     = e0;
      pre_i[(node0 + 2*duo + 1)*128 + o] = e1;
    } else {
      unsigned int l0 = f2bf(e0), l1 = f2bf(e1);
      unsigned int x0 = (unsigned int)__shfl_xor((int)l0, 1);
      unsigned int x1 = (unsigned int)__shfl_xor((int)l1, 1);
      if ((o & 1) == 0) {
        prejbf[(node0 + 2*duo)*64 + (o >> 1)]     = l0 | (x0 << 16);
        prejbf[(node0 + 2*duo + 1)*64 + (o >> 1)] = l1 | (x1 << 16);
      }
    }
  }
}

// ---------------------------------------------------------------------------
// edgepool: c_aniso_sum[node] = (sum_j ssp(pre_i+be1+pre_j)) @ We2 + be2*nn
// Direct L2 gather of pre_j rows, padded loop + exact pad-subtraction.
// s_s stage folded into the We2 matvec (reads sred pairs directly).
// ---------------------------------------------------------------------------
__global__ __launch_bounds__(512) void edgepool_kernel(
    const float* __restrict__ pre_i, const unsigned int* __restrict__ prejbf,
    const unsigned int* __restrict__ ent, const int* __restrict__ cnt,
    const float* __restrict__ be1, const float* __restrict__ We2,
    const float* __restrict__ be2, float* __restrict__ out) {
  __shared__ unsigned int ent_s[4][128];
  __shared__ float pis[4][128];
  __shared__ float sred[8][128];
  __shared__ float r2[4][8][16];
  __shared__ int nn_s[4];
  int t = threadIdx.x;
  int blk = (int)blockIdx.x;
  int Lb = ((blk & 7) << 6) | (blk >> 3);   // XCD-affinity swizzle (512)
  int node0 = Lb * 4;
  int b = Lb >> 5;
  const unsigned int* pjb = prejbf + (b << 13);
  { int ii = t >> 7, f = t & 127;
    pis[ii][f] = pre_i[(node0 + ii)*128 + f] + be1[f];
    ent_s[ii][f] = ent[(node0 + ii)*128 + f]; }
  if (t < 4) nn_s[t] = cnt[node0 + t];
  __syncthreads();
  int w = t >> 6, lane = t & 63;
  int ii = w >> 1, par = w & 1;
  float pia = pis[ii][2*lane];
  float pib = pis[ii][2*lane + 1];
  int cw = nn_s[ii];
  int nn = cw & 0xffff, nnp = cw >> 16;
  float a0 = 0.f, a1 = 0.f;
  for (int e = par; e < nnp; e += 8) {
    unsigned int u0 = ent_s[ii][e],     u1 = ent_s[ii][e + 2];
    unsigned int u2 = ent_s[ii][e + 4], u3 = ent_s[ii][e + 6];
    unsigned int v0 = pjb[(u0 & 127)*64 + lane];
    unsigned int v1 = pjb[(u1 & 127)*64 + lane];
    unsigned int v2 = pjb[(u2 & 127)*64 + lane];
    unsigned int v3 = pjb[(u3 & 127)*64 + lane];
    a0 += sspf(pia + bflo(v0)) + sspf(pia + bflo(v1))
        + sspf(pia + bflo(v2)) + sspf(pia + bflo(v3));
    a1 += sspf(pib + bfhi(v0)) + sspf(pib + bfhi(v1))
        + sspf(pib + bfhi(v2)) + sspf(pib + bfhi(v3));
  }
  // exact pad correction: pads (e in [nn,nnp)) read row j=0
  int npad = nnp - nn;
  int cp = (npad >> 1) + (((npad & 1) != 0 && (nn & 1) == par) ? 1 : 0);
  if (cp > 0) {
    unsigned int v0 = pjb[lane];
    a0 -= (float)cp * sspf(pia + bflo(v0));
    a1 -= (float)cp * sspf(pib + bfhi(v0));
  }
  *(float2*)&sred[w][2*lane] = make_float2(a0, a1);
  __syncthreads();
  { int i2 = t >> 7, o = t & 15, sg = (t >> 4) & 7;
    float p = 0.f;
    for (int f = sg*16; f < sg*16 + 16; f++)
      p += (sred[2*i2][f] + sred[2*i2+1][f]) * We2[f*16 + o];
    r2[i2][sg][o] = p; }
  __syncthreads();
  if (t < 64) {
    int i2 = t >> 4, o = t & 15;
    float v = be2[o] * (float)(nn_s[i2] & 0xffff);
    for (int sg = 0; sg < 8; sg++) v += r2[i2][sg][o];
    out[(node0 + i2)*16 + o] = v;
  }
}

// ---------------------------------------------------------------------------
extern "C" void kernel_launch(void* const* d_in, const int* in_sizes, int n_in,
                              void* d_out, int out_size, void* d_ws, size_t ws_size,
                              hipStream_t stream) {
  const float* coords = (const float*)d_in[0];
  const int*   species= (const int*)  d_in[1];
  const float* emb    = (const float*)d_in[2];
  const float* Wc1    = (const float*)d_in[3];
  const float* bc1    = (const float*)d_in[4];
  const float* Wc2    = (const float*)d_in[5];
  const float* bc2    = (const float*)d_in[6];
  const float* Wu1    = (const float*)d_in[7];
  const float* bu1    = (const float*)d_in[8];
  const float* Wu2    = (const float*)d_in[9];
  const float* bu2    = (const float*)d_in[10];
  const float* Wp1    = (const float*)d_in[11];
  const float* bp1    = (const float*)d_in[12];
  const float* Wp2    = (const float*)d_in[13];
  const float* bp2    = (const float*)d_in[14];
  const float* Wei    = (const float*)d_in[15];
  const float* Wej    = (const float*)d_in[16];
  const float* be1    = (const float*)d_in[17];
  const float* We2    = (const float*)d_in[18];
  const float* be2    = (const float*)d_in[19];
  float* out = (float*)d_out;

  float* wsf = (float*)d_ws;
  unsigned int* tb16   = (unsigned int*)wsf;               //  262,208 uints (4097x64)
  float*        h_a    = wsf + 524416;                     //  262,144
  float*        h_b    = wsf + 786560;                     //  262,144
  float*        pre_i  = wsf + 1048704;                    //  262,144
  unsigned int* hbf_a  = (unsigned int*)(wsf + 1310848);   //  131,072
  unsigned int* hbf_b  = (unsigned int*)(wsf + 1441920);   //  131,072
  unsigned int* prejbf = (unsigned int*)(wsf + 1572992);   //  131,072
  unsigned int* ent    = (unsigned int*)(wsf + 1704064);   //  262,144
  int*          cnt    = (int*)(wsf + 1966208);            //  2,048
  (void)in_sizes; (void)n_in; (void)out_size; (void)ws_size;

  prep_kernel<<<1536, 256, 0, stream>>>(coords, species, emb, Wc1, bc1, Wc2, bc2,
                                        tb16, h_a, hbf_a, ent, cnt);
  conv_t<false><<<512, 512, 0, stream>>>(
      h_a, hbf_a, h_b, hbf_b, tb16, ent, cnt,
      Wu1, bu1, Wu2, bu2,
      nullptr, nullptr, nullptr, nullptr, nullptr, nullptr, nullptr, nullptr, nullptr);
  conv_t<false><<<512, 512, 0, stream>>>(
      h_b, hbf_b, h_a, hbf_a, tb16, ent, cnt,
      Wu1, bu1, Wu2, bu2,
      nullptr, nullptr, nullptr, nullptr, nullptr, nullptr, nullptr, nullptr, nullptr);
  conv_t<true><<<512, 512, 0, stream>>>(
      h_a, hbf_a, nullptr, nullptr, tb16, ent, cnt,
      Wu1, bu1, Wu2, bu2,
      Wp1, bp1, Wp2, bp2, Wei, Wej, pre_i, prejbf, out);
  edgepool_kernel<<<512, 512, 0, stream>>>(pre_i, prejbf, ent, cnt, be1, We2, be2,
                                           out + 16384);
}

// Round 10
// 53.117 us; speedup vs baseline: 1.2690x; 1.2690x over previous
//
#include <hip/hip_runtime.h>

// MPDNN SchNet-style MPNN, 5-dispatch pipeline. R10 = exact revert to R8 (53.2us).
// R9 (shuffle-reduce update net) regressed to 67.4: broke per-wave weight-load
// coalescing (1x256B -> 4x64B transactions) + doubled LDS reads; barriers were
// already hidden by the co-resident block's waves (cf. learn_hip m114).
// R2: cooperative grid.sync ~120us/barrier on gfx950 -> multi-dispatch chain.
// R8: XCD-affinity swizzle + direct-L2 gathers + no LDS h-staging.
//  - Wf(d) -> 4096-row bf16 lookup table (1 MB, per-XCD L2 copy)
//  - compact neighbor lists (d<6, ~23% dense), entry = j | (table_row<<7)
//  - h fp32 (residual) + producer-packed bf16 (message gathers)
//  - conv3 fuses NodePool + pre_i/pre_j; c_aniso.sum(j) pushed through @We2

#define LN2F 0.69314718055994531f

__device__ __forceinline__ float sspf(float x) {          // softplus(x) - ln2, stable
  float e = __expf(-fabsf(x));
  return fmaxf(x, 0.0f) + __logf(1.0f + e) - LN2F;
}
__device__ __forceinline__ unsigned int f2bf(float x) {   // fp32 -> bf16 bits (RNE)
  unsigned int u = __float_as_uint(x);
  return (u + 0x7fffu + ((u >> 16) & 1u)) >> 16;
}
__device__ __forceinline__ float bflo(unsigned int u) { return __uint_as_float(u << 16); }
__device__ __forceinline__ float bfhi(unsigned int u) { return __uint_as_float(u & 0xffff0000u); }

// ---------------------------------------------------------------------------
// prep: blocks [0,1024): neighbor lists + h/hbf materialize (2 nodes/block),
//       swizzled so batch b lands on XCD b/2. Pad lists to x16.
//       blocks [1024,1536): filter table, 8 d-samples/block, bf16x2-packed.
// ---------------------------------------------------------------------------
__global__ __launch_bounds__(256) void prep_kernel(
    const float* __restrict__ coords, const int* __restrict__ species,
    const float* __restrict__ emb,
    const float* __restrict__ Wc1, const float* __restrict__ bc1,
    const float* __restrict__ Wc2, const float* __restrict__ bc2,
    unsigned int* __restrict__ tb16, float* __restrict__ h_a,
    unsigned int* __restrict__ hbf_a,
    unsigned int* __restrict__ ent, int* __restrict__ cnt) {
  int t = threadIdx.x;
  if (blockIdx.x < 1024) {
    __shared__ int wc[4];
    int blk = (int)blockIdx.x;
    int Lb = ((blk & 7) << 7) | (blk >> 3);         // XCD-affinity swizzle (1024)
    int node = Lb * 2 + (t >> 7);
    int j = t & 127;
    int b = node >> 7, i = node & 127;
    const float* cb = coords + (b << 7) * 3;
    float dx = cb[i*3+0] - cb[j*3+0];
    float dy = cb[i*3+1] - cb[j*3+1];
    float dz = cb[i*3+2] - cb[j*3+2];
    float d  = sqrtf(dx*dx + dy*dy + dz*dz);
    bool valid = (d < 6.0f) && (j != i);
    int k = 4096;                                   // 4096 = zero table row (pad)
    if (valid) { k = (int)(d * (4096.0f/6.0f)); if (k > 4095) k = 4095; }
    unsigned long long bal = __ballot(valid);
    int lane = t & 63, w = t >> 6;
    if (lane == 0) wc[w] = (int)__popcll(bal);
    __syncthreads();
    int ii = t >> 7;
    int nn = wc[2*ii] + wc[2*ii+1];
    int base = ((w & 1) ? wc[w-1] : 0) + (int)__popcll(bal & ((1ull << lane) - 1ull));
    if (valid) ent[node*128 + base] = (unsigned int)(j | (k << 7));
    int nnp = (nn + 15) & ~15;                      // pad x16 (8-deep gather)
    if (nnp > 128) nnp = 128;
    if (j >= nn && j < nnp) ent[node*128 + j] = (4096u << 7);
    if (j == 0) cnt[node] = nn | (nnp << 16);
    // materialize h0 = emb[species]
    float hv = emb[species[node]*128 + j];
    h_a[node*128 + j] = hv;
    unsigned int lo = f2bf(hv);
    unsigned int hi = (unsigned int)__shfl_xor((int)lo, 1);
    if ((j & 1) == 0) hbf_a[node*64 + (j >> 1)] = lo | (hi << 16);
  } else {
    __shared__ float rbf[8][32];
    __shared__ float hid[8][128];
    int tb = (int)blockIdx.x - 1024;                // 0..511
    int t0 = tb * 8;
    { int tt = t >> 5, kk = t & 31;                 // 256 threads = 8x32 exactly
      float d = (float)(t0 + tt) * (6.0f/4096.0f) + 0.5f * (6.0f/4096.0f);
      float mu = 0.5f + (float)kk * (5.5f/31.0f);
      float z = d - mu;
      rbf[tt][kk] = __expf(-8.0f * z * z); }        // 1/(2*0.25^2)=8
    __syncthreads();
    int f = t & 127, sub = t >> 7;                  // sub in 0..1 -> rows sub*4..+3
    float s0 = bc1[f], s1 = s0, s2 = s0, s3 = s0;
    int r0 = sub * 4;
    for (int kk = 0; kk < 32; kk++) {
      float wv = Wc1[kk*128 + f];
      s0 += rbf[r0+0][kk]*wv; s1 += rbf[r0+1][kk]*wv;
      s2 += rbf[r0+2][kk]*wv; s3 += rbf[r0+3][kk]*wv;
    }
    hid[r0+0][f] = sspf(s0); hid[r0+1][f] = sspf(s1);
    hid[r0+2][f] = sspf(s2); hid[r0+3][f] = sspf(s3);
    __syncthreads();
    float o0 = bc2[f], o1 = o0, o2 = o0, o3 = o0;
    for (int g = 0; g < 128; g++) {
      float wv = Wc2[g*128 + f];
      o0 += hid[r0+0][g]*wv; o1 += hid[r0+1][g]*wv;
      o2 += hid[r0+2][g]*wv; o3 += hid[r0+3][g]*wv;
    }
    unsigned int l0 = f2bf(o0), l1 = f2bf(o1), l2 = f2bf(o2), l3 = f2bf(o3);
    unsigned int p0 = (unsigned int)__shfl_xor((int)l0, 1);
    unsigned int p1 = (unsigned int)__shfl_xor((int)l1, 1);
    unsigned int p2 = (unsigned int)__shfl_xor((int)l2, 1);
    unsigned int p3 = (unsigned int)__shfl_xor((int)l3, 1);
    if ((f & 1) == 0) {
      int fw = f >> 1;
      tb16[(t0+r0+0)*64 + fw] = l0 | (p0 << 16);
      tb16[(t0+r0+1)*64 + fw] = l1 | (p1 << 16);
      tb16[(t0+r0+2)*64 + fw] = l2 | (p2 << 16);
      tb16[(t0+r0+3)*64 + fw] = l3 | (p3 << 16);
    }
    if (tb == 0 && t < 64) tb16[4096*64 + t] = 0u;  // zero pad row
  }
}

// ---------------------------------------------------------------------------
// conv: one block = 4 nodes (swizzled). Direct L2 gather of table + hbf rows
// (8 in flight each), no LDS h-staging. Update net 4-rows-per-weight-load.
// LAST: skip h stores; fuse NodePool (c_iso) + pre_i/pre_j.
// ---------------------------------------------------------------------------
template<bool LAST>
__global__ __launch_bounds__(512) void conv_t(
    const float* __restrict__ h_in, const unsigned int* __restrict__ hbf_in,
    float* __restrict__ h_out, unsigned int* __restrict__ hbf_out,
    const unsigned int* __restrict__ tb16, const unsigned int* __restrict__ ent,
    const int* __restrict__ cnt,
    const float* __restrict__ Wu1, const float* __restrict__ bu1,
    const float* __restrict__ Wu2, const float* __restrict__ bu2,
    const float* __restrict__ Wp1, const float* __restrict__ bp1,
    const float* __restrict__ Wp2, const float* __restrict__ bp2,
    const float* __restrict__ Wei, const float* __restrict__ Wej,
    float* __restrict__ pre_i, unsigned int* __restrict__ prejbf,
    float* __restrict__ out) {
  __shared__ unsigned int ent_s[4][128];
  __shared__ float mred[8][128];
  __shared__ float m_s[4][128];
  __shared__ float red[4][4][128];
  __shared__ float u1_s[4][128];
  __shared__ int nn_s[4];
  int t = threadIdx.x;
  int blk = (int)blockIdx.x;
  int Lb = ((blk & 7) << 6) | (blk >> 3);   // XCD-affinity swizzle (512)
  int node0 = Lb * 4;
  int b = Lb >> 5;
  const unsigned int* hb = hbf_in + (b << 13);   // batch's bf16 h panel (L2)

  { int ii = t >> 7, f = t & 127;
    ent_s[ii][f] = ent[(node0 + ii)*128 + f]; }
  if (t < 4) nn_s[t] = cnt[node0 + t];
  __syncthreads();

  // --- message: wave pair by parity, 8 table + 8 h gathers in flight ---
  int w = t >> 6, lane = t & 63;
  int ii = w >> 1, par = w & 1;
  int nnp = nn_s[ii] >> 16;                 // padded count (multiple of 16)
  float a0 = 0.f, a1 = 0.f, b0 = 0.f, b1 = 0.f;
  float c0 = 0.f, c1 = 0.f, d0 = 0.f, d1 = 0.f;
  for (int e = par; e < nnp; e += 16) {
    unsigned int u0 = ent_s[ii][e],      u1 = ent_s[ii][e + 2];
    unsigned int u2 = ent_s[ii][e + 4],  u3 = ent_s[ii][e + 6];
    unsigned int u4 = ent_s[ii][e + 8],  u5 = ent_s[ii][e + 10];
    unsigned int u6 = ent_s[ii][e + 12], u7 = ent_s[ii][e + 14];
    unsigned int t0 = tb16[(u0 >> 7)*64 + lane];
    unsigned int t1 = tb16[(u1 >> 7)*64 + lane];
    unsigned int t2 = tb16[(u2 >> 7)*64 + lane];
    unsigned int t3 = tb16[(u3 >> 7)*64 + lane];
    unsigned int t4 = tb16[(u4 >> 7)*64 + lane];
    unsigned int t5 = tb16[(u5 >> 7)*64 + lane];
    unsigned int t6 = tb16[(u6 >> 7)*64 + lane];
    unsigned int t7 = tb16[(u7 >> 7)*64 + lane];
    unsigned int h0 = hb[(u0 & 127)*64 + lane];
    unsigned int h1 = hb[(u1 & 127)*64 + lane];
    unsigned int h2 = hb[(u2 & 127)*64 + lane];
    unsigned int h3 = hb[(u3 & 127)*64 + lane];
    unsigned int h4 = hb[(u4 & 127)*64 + lane];
    unsigned int h5 = hb[(u5 & 127)*64 + lane];
    unsigned int h6 = hb[(u6 & 127)*64 + lane];
    unsigned int h7 = hb[(u7 & 127)*64 + lane];
    a0 += bflo(t0) * bflo(h0); a1 += bfhi(t0) * bfhi(h0);
    b0 += bflo(t1) * bflo(h1); b1 += bfhi(t1) * bfhi(h1);
    c0 += bflo(t2) * bflo(h2); c1 += bfhi(t2) * bfhi(h2);
    d0 += bflo(t3) * bflo(h3); d1 += bfhi(t3) * bfhi(h3);
    a0 += bflo(t4) * bflo(h4); a1 += bfhi(t4) * bfhi(h4);
    b0 += bflo(t5) * bflo(h5); b1 += bfhi(t5) * bfhi(h5);
    c0 += bflo(t6) * bflo(h6); c1 += bfhi(t6) * bfhi(h6);
    d0 += bflo(t7) * bflo(h7); d1 += bfhi(t7) * bfhi(h7);
  }
  a0 += b0 + c0 + d0; a1 += b1 + c1 + d1;
  *(float2*)&mred[w][2*lane] = make_float2(a0, a1);
  __syncthreads();
  { int i2 = t >> 7, f = t & 127;
    m_s[i2][f] = mred[2*i2][f] + mred[2*i2+1][f]; }
  __syncthreads();

  // --- update net, 4 rows batched per weight load ---
  int g = t & 127, q = t >> 7;
  {
    float p0=0,p1=0,p2=0,p3=0;
    for (int f = q*32; f < q*32 + 32; f++) {
      float wv = Wu1[f*128 + g];
      p0 += m_s[0][f]*wv; p1 += m_s[1][f]*wv; p2 += m_s[2][f]*wv; p3 += m_s[3][f]*wv;
    }
    red[q][0][g]=p0; red[q][1][g]=p1; red[q][2][g]=p2; red[q][3][g]=p3;
  }
  __syncthreads();
  { int i2 = t >> 7, gg = t & 127;
    u1_s[i2][gg] = sspf(red[0][i2][gg]+red[1][i2][gg]+red[2][i2][gg]+red[3][i2][gg] + bu1[gg]); }
  __syncthreads();
  {
    float p0=0,p1=0,p2=0,p3=0;
    for (int f = q*32; f < q*32 + 32; f++) {
      float wv = Wu2[f*128 + g];
      p0 += u1_s[0][f]*wv; p1 += u1_s[1][f]*wv; p2 += u1_s[2][f]*wv; p3 += u1_s[3][f]*wv;
    }
    red[q][0][g]=p0; red[q][1][g]=p1; red[q][2][g]=p2; red[q][3][g]=p3;
  }
  __syncthreads();
  { int i2 = t >> 7, o = t & 127;
    int node = node0 + i2;
    float delta = red[0][i2][o]+red[1][i2][o]+red[2][i2][o]+red[3][i2][o] + bu2[o];
    float hf = h_in[node*128 + o] + delta;
    if constexpr (!LAST) {
      h_out[node*128 + o] = hf;
      unsigned int lo = f2bf(hf);
      unsigned int hi = (unsigned int)__shfl_xor((int)lo, 1);
      if ((o & 1) == 0) hbf_out[node*64 + (o >> 1)] = lo | (hi << 16);
    } else {
      u1_s[i2][o] = hf;                     // u1 dead here; keep h for pools
    }
  }
  if constexpr (LAST) {
    __syncthreads();
    float (*hs)[128]     = u1_s;
    float (*redp)[4][64] = reinterpret_cast<float (*)[4][64]>(red);
    float (*us)[64]      = reinterpret_cast<float (*)[64]>(m_s);
    int gp = t & 63, qp = t >> 6;           // qp 0..7 -> 16-wide f segment
    float p0=0,p1=0,p2=0,p3=0;
    for (int f = qp*16; f < qp*16 + 16; f++) {
      float wv = Wp1[f*64 + gp];
      p0 += hs[0][f]*wv; p1 += hs[1][f]*wv; p2 += hs[2][f]*wv; p3 += hs[3][f]*wv;
    }
    redp[qp][0][gp]=p0; redp[qp][1][gp]=p1; redp[qp][2][gp]=p2; redp[qp][3][gp]=p3;
    __syncthreads();
    if (t < 256) {
      int i4 = t >> 6, gg = t & 63;
      float s = bp1[gg];
      for (int q2 = 0; q2 < 8; q2++) s += redp[q2][i4][gg];
      us[i4][gg] = sspf(s);
    }
    __syncthreads();
    if (t < 32) {
      int i4 = t >> 3, o = t & 7;
      float v = bp2[o];
      for (int gg = 0; gg < 64; gg++) v += us[i4][gg] * Wp2[gg*8 + o];
      out[(node0 + i4)*8 + o] = v;
    }
    int o = t & 127, sel = (t >> 7) & 1, duo = t >> 8;
    const float* W = sel ? Wej : Wei;
    float q0 = 0.f, q1 = 0.f;
    for (int f = 0; f < 128; f++) {
      float wv = W[f*128 + o];
      q0 += hs[2*duo][f]*wv; q1 += hs[2*duo+1][f]*wv;
    }
    if (sel == 0) {
      pre_i[(node0 + 2*duo)*128 + o]     = q0;
      pre_i[(node0 + 2*duo + 1)*128 + o] = q1;
    } else {
      unsigned int l0 = f2bf(q0), l1 = f2bf(q1);
      unsigned int h0 = (unsigned int)__shfl_xor((int)l0, 1);
      unsigned int h1 = (unsigned int)__shfl_xor((int)l1, 1);
      if ((o & 1) == 0) {
        prejbf[(node0 + 2*duo)*64 + (o >> 1)]     = l0 | (h0 << 16);
        prejbf[(node0 + 2*duo + 1)*64 + (o >> 1)] = l1 | (h1 << 16);
      }
    }
  }
}

// ---------------------------------------------------------------------------
// edgepool: c_aniso_sum[node] = (sum_j ssp(pre_i+be1+pre_j)) @ We2 + be2*nn
// Direct L2 gather of pre_j rows, padded loop + exact pad-subtraction
// (pad entries alias j=0; subtract cp * ssp(pia + row0)).
// ---------------------------------------------------------------------------
__global__ __launch_bounds__(512) void edgepool_kernel(
    const float* __restrict__ pre_i, const unsigned int* __restrict__ prejbf,
    const unsigned int* __restrict__ ent, const int* __restrict__ cnt,
    const float* __restrict__ be1, const float* __restrict__ We2,
    const float* __restrict__ be2, float* __restrict__ out) {
  __shared__ unsigned int ent_s[4][128];
  __shared__ float pis[4][128];
  __shared__ float sred[8][128];
  __shared__ float s_s[4][128];
  __shared__ float r2[4][8][16];
  __shared__ int nn_s[4];
  int t = threadIdx.x;
  int blk = (int)blockIdx.x;
  int Lb = ((blk & 7) << 6) | (blk >> 3);   // XCD-affinity swizzle (512)
  int node0 = Lb * 4;
  int b = Lb >> 5;
  const unsigned int* pjb = prejbf + (b << 13);
  { int ii = t >> 7, f = t & 127;
    pis[ii][f] = pre_i[(node0 + ii)*128 + f] + be1[f];
    ent_s[ii][f] = ent[(node0 + ii)*128 + f]; }
  if (t < 4) nn_s[t] = cnt[node0 + t];
  __syncthreads();
  int w = t >> 6, lane = t & 63;
  int ii = w >> 1, par = w & 1;
  float pia = pis[ii][2*lane];
  float pib = pis[ii][2*lane + 1];
  int cw = nn_s[ii];
  int nn = cw & 0xffff, nnp = cw >> 16;
  float a0 = 0.f, a1 = 0.f;
  for (int e = par; e < nnp; e += 8) {
    unsigned int u0 = ent_s[ii][e],     u1 = ent_s[ii][e + 2];
    unsigned int u2 = ent_s[ii][e + 4], u3 = ent_s[ii][e + 6];
    unsigned int v0 = pjb[(u0 & 127)*64 + lane];
    unsigned int v1 = pjb[(u1 & 127)*64 + lane];
    unsigned int v2 = pjb[(u2 & 127)*64 + lane];
    unsigned int v3 = pjb[(u3 & 127)*64 + lane];
    a0 += sspf(pia + bflo(v0)) + sspf(pia + bflo(v1))
        + sspf(pia + bflo(v2)) + sspf(pia + bflo(v3));
    a1 += sspf(pib + bfhi(v0)) + sspf(pib + bfhi(v1))
        + sspf(pib + bfhi(v2)) + sspf(pib + bfhi(v3));
  }
  // exact pad correction: pads (e in [nn,nnp)) read row j=0
  int npad = nnp - nn;
  int cp = (npad >> 1) + (((npad & 1) != 0 && (nn & 1) == par) ? 1 : 0);
  if (cp > 0) {
    unsigned int v0 = pjb[lane];
    a0 -= (float)cp * sspf(pia + bflo(v0));
    a1 -= (float)cp * sspf(pib + bfhi(v0));
  }
  *(float2*)&sred[w][2*lane] = make_float2(a0, a1);
  __syncthreads();
  { int i2 = t >> 7, f = t & 127;
    s_s[i2][f] = sred[2*i2][f] + sred[2*i2+1][f]; }
  __syncthreads();
  { int i2 = t >> 7, o = t & 15, seg = (t >> 4) & 7;
    float p = 0.f;
    for (int f = seg*16; f < seg*16 + 16; f++) p += s_s[i2][f] * We2[f*16 + o];
    r2[i2][seg][o] = p; }
  __syncthreads();
  if (t < 64) {
    int i2 = t >> 4, o = t & 15;
    float v = be2[o] * (float)(nn_s[i2] & 0xffff);
    for (int seg = 0; seg < 8; seg++) v += r2[i2][seg][o];
    out[(node0 + i2)*16 + o] = v;
  }
}

// ---------------------------------------------------------------------------
extern "C" void kernel_launch(void* const* d_in, const int* in_sizes, int n_in,
                              void* d_out, int out_size, void* d_ws, size_t ws_size,
                              hipStream_t stream) {
  const float* coords = (const float*)d_in[0];
  const int*   species= (const int*)  d_in[1];
  const float* emb    = (const float*)d_in[2];
  const float* Wc1    = (const float*)d_in[3];
  const float* bc1    = (const float*)d_in[4];
  const float* Wc2    = (const float*)d_in[5];
  const float* bc2    = (const float*)d_in[6];
  const float* Wu1    = (const float*)d_in[7];
  const float* bu1    = (const float*)d_in[8];
  const float* Wu2    = (const float*)d_in[9];
  const float* bu2    = (const float*)d_in[10];
  const float* Wp1    = (const float*)d_in[11];
  const float* bp1    = (const float*)d_in[12];
  const float* Wp2    = (const float*)d_in[13];
  const float* bp2    = (const float*)d_in[14];
  const float* Wei    = (const float*)d_in[15];
  const float* Wej    = (const float*)d_in[16];
  const float* be1    = (const float*)d_in[17];
  const float* We2    = (const float*)d_in[18];
  const float* be2    = (const float*)d_in[19];
  float* out = (float*)d_out;

  float* wsf = (float*)d_ws;
  unsigned int* tb16   = (unsigned int*)wsf;               //  262,208 uints (4097x64)
  float*        h_a    = wsf + 524416;                     //  262,144
  float*        h_b    = wsf + 786560;                     //  262,144
  float*        pre_i  = wsf + 1048704;                    //  262,144
  unsigned int* hbf_a  = (unsigned int*)(wsf + 1310848);   //  131,072
  unsigned int* hbf_b  = (unsigned int*)(wsf + 1441920);   //  131,072
  unsigned int* prejbf = (unsigned int*)(wsf + 1572992);   //  131,072
  unsigned int* ent    = (unsigned int*)(wsf + 1704064);   //  262,144
  int*          cnt    = (int*)(wsf + 1966208);            //  2,048
  (void)in_sizes; (void)n_in; (void)out_size; (void)ws_size;

  prep_kernel<<<1536, 256, 0, stream>>>(coords, species, emb, Wc1, bc1, Wc2, bc2,
                                        tb16, h_a, hbf_a, ent, cnt);
  conv_t<false><<<512, 512, 0, stream>>>(
      h_a, hbf_a, h_b, hbf_b, tb16, ent, cnt,
      Wu1, bu1, Wu2, bu2,
      nullptr, nullptr, nullptr, nullptr, nullptr, nullptr, nullptr, nullptr, nullptr);
  conv_t<false><<<512, 512, 0, stream>>>(
      h_b, hbf_b, h_a, hbf_a, tb16, ent, cnt,
      Wu1, bu1, Wu2, bu2,
      nullptr, nullptr, nullptr, nullptr, nullptr, nullptr, nullptr, nullptr, nullptr);
  conv_t<true><<<512, 512, 0, stream>>>(
      h_a, hbf_a, nullptr, nullptr, tb16, ent, cnt,
      Wu1, bu1, Wu2, bu2,
      Wp1, bp1, Wp2, bp2, Wei, Wej, pre_i, prejbf, out);
  edgepool_kernel<<<512, 512, 0, stream>>>(pre_i, prejbf, ent, cnt, be1, We2, be2,
                                           out + 16384);
}